// Round 10
// baseline (304.225 us; speedup 1.0000x reference)
//
#include <hip/hip_runtime.h>
#include <math.h>

typedef float floatx4 __attribute__((ext_vector_type(4)));

#define NAG   32
#define NOBS  16
#define NN    80
#define KK    5
#define EKNN  400   // NN*KK
#define ED    416   // EKNN + NOBS
#define HID   128
#define TPB   1024

// swizzle for bf16 rows (32 uint2-chunks of 4 bf16 per row)
__device__ __forceinline__ int hswz(int n, int p) { return p ^ ((n & 3) << 3); }

__device__ __forceinline__ float bfhi_f(unsigned u) {
    union { unsigned u; float f; } v; v.u = u & 0xffff0000u; return v.f;
}
__device__ __forceinline__ float bflo_f(unsigned u) {
    union { unsigned u; float f; } v; v.u = u << 16; return v.f;
}
__device__ __forceinline__ unsigned f_bf_rne(float f) {   // 16-bit bf16 in low bits
    union { float f; unsigned u; } v; v.f = f;
    return (v.u + 0x7fffu + ((v.u >> 16) & 1u)) >> 16;
}
__device__ __forceinline__ uint2 pack_bf4(float a, float b, float c, float d) {
    uint2 r;
    r.x = f_bf_rne(a) | (f_bf_rne(b) << 16);
    r.y = f_bf_rne(c) | (f_bf_rne(d) << 16);
    return r;
}
__device__ __forceinline__ void unpack_bf4(uint2 p, float* o) {
    o[0] = bflo_f(p.x); o[1] = bfhi_f(p.x);
    o[2] = bflo_f(p.y); o[3] = bfhi_f(p.y);
}

// ---- dual node-linear: xl = h@Wl + bl (bf16->xlB), xr = h@Wr + br (bf16->hxr) ----
// thread: m = t&1 (Wl vs Wr), q = (t>>1)&31 (float4 out col), ng = t>>6 (5 nodes).
// Each h row is read ONLY by its owning wave, and xr[n] is written by that same
// wave after all its reads (lockstep) -> xr safely overwrites h in hxrS.
template<int F_IN>
__device__ __forceinline__ void node_linear(const float* xf, const uint2* hxr_in,
    const float* __restrict__ Wl, const float* __restrict__ bl,
    const float* __restrict__ Wr, const float* __restrict__ br,
    uint2* xlB, uint2* hxr_out, int t)
{
    const int m  = t & 1;
    const int q  = (t >> 1) & 31;
    const int ng = t >> 6;                 // 0..15 (wave-uniform)
    const float* __restrict__ W  = m ? Wr : Wl;
    const float* __restrict__ bv = m ? br : bl;
    uint2* dstB = m ? hxr_out : xlB;
    const int nbase = ng * 5;

    float acc[5][4];
#pragma unroll
    for (int a = 0; a < 5; a++)
#pragma unroll
        for (int c = 0; c < 4; c++) acc[a][c] = 0.f;

    if constexpr (F_IN == 5) {
#pragma unroll
        for (int fi = 0; fi < 5; ++fi) {
            floatx4 wv = *(const floatx4*)(W + fi*HID + q*4);
            float hv[5];
#pragma unroll
            for (int a = 0; a < 5; a++) hv[a] = xf[(nbase + a)*5 + fi];
#pragma unroll
            for (int a = 0; a < 5; a++)
#pragma unroll
                for (int c = 0; c < 4; c++) acc[a][c] += hv[a]*wv[c];
        }
    } else {
        int rowoff[5], rsw[5];
#pragma unroll
        for (int a = 0; a < 5; a++) { int n = nbase + a; rowoff[a] = n*32; rsw[a] = (n & 3) << 3; }
#pragma unroll 1
        for (int f4 = 0; f4 < F_IN/4; ++f4) {
            uint2 p[5];
#pragma unroll
            for (int a = 0; a < 5; a++)
                p[a] = hxr_in[rowoff[a] + (f4 ^ rsw[a])];
#pragma unroll
            for (int u = 0; u < 4; u++) {
                floatx4 wv = *(const floatx4*)(W + (f4*4 + u)*HID + q*4);
#pragma unroll
                for (int a = 0; a < 5; a++) {
                    unsigned w = (u < 2) ? p[a].x : p[a].y;
                    float h = (u & 1) ? bfhi_f(w) : bflo_f(w);
#pragma unroll
                    for (int c = 0; c < 4; c++) acc[a][c] += h*wv[c];
                }
            }
        }
    }

    floatx4 b4 = *(const floatx4*)(bv + q*4);
#pragma unroll
    for (int a = 0; a < 5; a++) {
        int n = nbase + a;
        dstB[n*32 + hswz(n, q)] =
            pack_bf4(acc[a][0]+b4[0], acc[a][1]+b4[1], acc[a][2]+b4[2], acc[a][3]+b4[3]);
    }
}

// ---- edge logits: lane owns float4 col q = t&31, group t>>5 owns 13 edges ----
__device__ __forceinline__ void edge_logits(const uint2* xlB, const uint2* xrB,
    const float* eaS, const int* nbr, const int* gmask,
    const float* __restrict__ We, const float* __restrict__ att,
    float* logitS, int t)
{
    const int q   = t & 31;
    const int grp = t >> 5;      // 0..31, edges grp*13 .. grp*13+12
    floatx4 w0 = *(const floatx4*)(We + 0*HID + q*4);
    floatx4 w1 = *(const floatx4*)(We + 1*HID + q*4);
    floatx4 w2 = *(const floatx4*)(We + 2*HID + q*4);
    floatx4 w3 = *(const floatx4*)(We + 3*HID + q*4);
    floatx4 w4 = *(const floatx4*)(We + 4*HID + q*4);
    floatx4 at = *(const floatx4*)(att + q*4);

#pragma unroll 1
    for (int i = 0; i < 13; i++) {
        int e = grp*13 + i;
        int src, dst; bool act = true;
        if (e < EKNN) { dst = e / KK; src = nbr[e]; }
        else { int j = e - EKNN; src = j; dst = j + NAG; act = (gmask[j] != 0); }
        float e0 = eaS[e*5+0], e1 = eaS[e*5+1], e2 = eaS[e*5+2],
              e3 = eaS[e*5+3], e4 = eaS[e*5+4];
        float vl[4], vr[4];
        unpack_bf4(xlB[src*32 + hswz(src, q)], vl);
        unpack_bf4(xrB[dst*32 + hswz(dst, q)], vr);
        float part = 0.f;
#pragma unroll
        for (int c = 0; c < 4; c++) {
            float s = vl[c] + vr[c] + e0*w0[c] + e1*w1[c] + e2*w2[c] + e3*w3[c] + e4*w4[c];
            s = fmaxf(s, 0.2f*s);   // leaky_relu(s, 0.2)
            part += s * at[c];
        }
        part += __shfl_xor(part, 16);
        part += __shfl_xor(part, 8);
        part += __shfl_xor(part, 4);
        part += __shfl_xor(part, 2);
        part += __shfl_xor(part, 1);
        if (q == 0 && act) logitS[e] = part;
    }
}

// ---- per-dst softmax over incoming edges (5 knn + optional goal edge) ----
__device__ __forceinline__ void seg_softmax(const float* logitS, const int* gmask,
                                            float* alphaS, int t)
{
    if (t < NN) {
        const int n = t;
        float l[KK];
#pragma unroll
        for (int k = 0; k < KK; k++) l[k] = logitS[n*KK + k];
        float m = l[0];
#pragma unroll
        for (int k = 1; k < KK; k++) m = fmaxf(m, l[k]);
        int ge = -1; float lg = 0.f;
        if (n >= NAG && n < NAG + NOBS && gmask[n - NAG]) {
            ge = EKNN + (n - NAG);
            lg = logitS[ge];
            m = fmaxf(m, lg);
        }
        float s = 0.f, av[KK];
#pragma unroll
        for (int k = 0; k < KK; k++) { av[k] = expf(l[k] - m); s += av[k]; }
        float ag = 0.f;
        if (ge >= 0) { ag = expf(lg - m); s += ag; }
        float inv = 1.f / s;
#pragma unroll
        for (int k = 0; k < KK; k++) alphaS[n*KK + k] = av[k]*inv;
        if (ge >= 0) alphaS[ge] = ag*inv;
    }
}

// ---- h[n][f] = relu(bias[f] + sum_e alpha_e * xl[src_e][f]) -> bf16 hxrS ----
__device__ __forceinline__ void aggregate(const uint2* xlB, const float* alphaS,
                                          const int* nbr, const int* gmask,
                                          const float* __restrict__ bias,
                                          uint2* hxr, int t)
{
    for (int idx = t; idx < NN*32; idx += TPB) {
        int n = idx >> 5;
        int c = idx & 31;
        floatx4 acc = *(const floatx4*)(bias + 4*c);
#pragma unroll
        for (int k = 0; k < KK; k++) {
            float a = alphaS[n*KK + k];
            int s = nbr[n*KK + k];
            float v[4];
            unpack_bf4(xlB[s*32 + hswz(s, c)], v);
#pragma unroll
            for (int q = 0; q < 4; q++) acc[q] += a * v[q];
        }
        if (n >= NAG && n < NAG + NOBS && gmask[n - NAG]) {
            float a = alphaS[EKNN + (n - NAG)];
            int s = n - NAG;
            float v[4];
            unpack_bf4(xlB[s*32 + hswz(s, c)], v);
#pragma unroll
            for (int q = 0; q < 4; q++) acc[q] += a * v[q];
        }
#pragma unroll
        for (int q = 0; q < 4; q++) acc[q] = fmaxf(acc[q], 0.f);
        hxr[n*32 + hswz(n, c)] = pack_bf4(acc[0], acc[1], acc[2], acc[3]);
    }
}

// VGPR cap 48 + LDS ~58KB: tests both co-residence hypotheses.
// r7: vgpr=32, LDS 78.8K -> 2 blocks (89%). r8/r9: vgpr=64/56, same LDS -> 1 block (47%).
// Either the VGPR pool needs <=48/wave for 8 waves/SIMD, or 2x78.8KB trips an LDS
// granule near the 160KB boundary. This build: 2x58KB = 116KB, vgpr 48.
__global__ __attribute__((amdgpu_flat_work_group_size(TPB, TPB), amdgpu_num_vgpr(48)))
void e3_kernel(
    const float* __restrict__ obst, const float* __restrict__ apos,
    const float* __restrict__ gpos, const float* __restrict__ avel,
    const float* __restrict__ Wl1, const float* __restrict__ bl1,
    const float* __restrict__ Wr1, const float* __restrict__ br1,
    const float* __restrict__ We1, const float* __restrict__ att1, const float* __restrict__ bias1,
    const float* __restrict__ Wl2, const float* __restrict__ bl2,
    const float* __restrict__ Wr2, const float* __restrict__ br2,
    const float* __restrict__ We2, const float* __restrict__ att2, const float* __restrict__ bias2,
    const float* __restrict__ Wl3, const float* __restrict__ bl3,
    const float* __restrict__ Wr3, const float* __restrict__ br3,
    const float* __restrict__ We3, const float* __restrict__ att3, const float* __restrict__ bias3,
    float* __restrict__ out)
{
    __shared__ float pos0[NN], pos1[NN], vel0[NN], vel1[NN], rad[NN];
    __shared__ float xfeat[NN*5];
    __shared__ int   nbr[NN*KK];
    __shared__ int   gmask[NOBS];
    __shared__ float eaS[ED*5];
    __shared__ float logitS[ED];
    __shared__ float alphaS[ED];
    __shared__ uint2 hxrS[NN*32];            // bf16 h AND bf16 xr (time-shared)
    __shared__ uint2 xlB[NN*32];             // bf16 xl
    __shared__ float xl3S[NN], xr3S[NN];
    __shared__ float resS;

    const int g = blockIdx.x;
    const int t = threadIdx.x;

    // ---------- phase A: load graph ----------
    if (t < NN) {
        int n = t;
        float px, py, vx = 0.f, vy = 0.f, r;
        if (n < NAG) {
            px = apos[(g*NAG + n)*2 + 0]; py = apos[(g*NAG + n)*2 + 1];
            vx = avel[(g*NAG + n)*2 + 0]; vy = avel[(g*NAG + n)*2 + 1];
            r = 0.05f;
        } else if (n < 2*NAG) {
            int m = n - NAG;
            px = gpos[(g*NAG + m)*2 + 0]; py = gpos[(g*NAG + m)*2 + 1];
            r = 0.f;
        } else {
            int m = n - 2*NAG;
            px = obst[(g*NOBS + m)*2 + 0]; py = obst[(g*NOBS + m)*2 + 1];
            r = 0.1f;
        }
        pos0[n] = px; pos1[n] = py; vel0[n] = vx; vel1[n] = vy; rad[n] = r;
        xfeat[n*5 + 0] = (n < NAG) ? 1.f : 0.f;
        xfeat[n*5 + 1] = (n >= NAG && n < 2*NAG) ? 1.f : 0.f;
        xfeat[n*5 + 2] = (n >= 2*NAG) ? 1.f : 0.f;
        xfeat[n*5 + 3] = (n < NAG) ? sqrtf(__fadd_rn(__fmul_rn(vx,vx), __fmul_rn(vy,vy))) : 0.f;
        xfeat[n*5 + 4] = r;
    }
    __syncthreads();

    // ---------- phase B: kNN top-5 (ascending d2, stable on ties == top_k) ----------
    if (t < NN) {
        const int i = t;
        float bd[KK]; int bi[KK];
#pragma unroll
        for (int k = 0; k < KK; k++) { bd[k] = 3.4e38f; bi[k] = -1; }
        const float pix = pos0[i], piy = pos1[i];
        for (int j = 0; j < NN; j++) {
            float dx = __fsub_rn(pix, pos0[j]);
            float dy = __fsub_rn(piy, pos1[j]);
            float d2 = __fadd_rn(__fmul_rn(dx,dx), __fmul_rn(dy,dy));
            if (d2 < bd[KK-1]) {
                int p = KK - 1;
                while (p > 0 && d2 < bd[p-1]) { bd[p] = bd[p-1]; bi[p] = bi[p-1]; p--; }
                bd[p] = d2; bi[p] = j;
            }
        }
#pragma unroll
        for (int k = 0; k < KK; k++) nbr[i*KK + k] = bi[k];
    }
    __syncthreads();

    // goal-edge dedup mask
    if (t < NOBS) {
        int j = t, dup = 0;
#pragma unroll
        for (int k = 0; k < KK; k++) dup |= (nbr[(NAG + j)*KK + k] == j);
        gmask[j] = !dup;
    }
    __syncthreads();

    // ---------- phase C: edge attributes ----------
    for (int e = t; e < ED; e += TPB) {
        int src, dst;
        if (e < EKNN) { dst = e / KK; src = nbr[e]; }
        else          { src = e - EKNN; dst = src + NAG; }
        float pdx = pos0[src] - pos0[dst];
        float pdy = pos1[src] - pos1[dst];
        float dist = sqrtf(pdx*pdx + pdy*pdy);
        float inv = 1.f / fmaxf(dist, 1e-6f);
        float pnx = pdx * inv, pny = pdy * inv;
        float rvx = vel0[src] - vel0[dst];
        float rvy = vel1[src] - vel1[dst];
        eaS[e*5 + 0] = (src < NAG && dst == src + NAG) ? 1.f : 0.f;
        eaS[e*5 + 1] = dist;
        eaS[e*5 + 2] = dist - (rad[src] + rad[dst]);
        eaS[e*5 + 3] = rvx*pnx + rvy*pny;
        eaS[e*5 + 4] = rvx*pny - rvy*pnx;
    }
    __syncthreads();

    // ================= layers 1 & 2 (F_out = 128) =================
    const float* WlA[2]   = { Wl1, Wl2 };
    const float* blA[2]   = { bl1, bl2 };
    const float* WrA[2]   = { Wr1, Wr2 };
    const float* brA[2]   = { br1, br2 };
    const float* WeA[2]   = { We1, We2 };
    const float* attA[2]  = { att1, att2 };
    const float* biasA[2] = { bias1, bias2 };

    for (int L = 0; L < 2; L++) {
        if (L == 0) node_linear<5>(xfeat, hxrS, WlA[0], blA[0], WrA[0], brA[0], xlB, hxrS, t);
        else        node_linear<HID>(xfeat, hxrS, WlA[1], blA[1], WrA[1], brA[1], xlB, hxrS, t);
        __syncthreads();

        edge_logits(xlB, hxrS, eaS, nbr, gmask, WeA[L], attA[L], logitS, t);
        __syncthreads();

        seg_softmax(logitS, gmask, alphaS, t);
        __syncthreads();

        aggregate(xlB, alphaS, nbr, gmask, biasA[L], hxrS, t);
        __syncthreads();
    }

    // ================= layer 3 (F_out = 1) =================
    // node transform: lane owns col q, group grp handles nodes grp, grp+32, grp+64
    {
        const int q   = t & 31;
        const int grp = t >> 5;
        floatx4 wl4 = *(const floatx4*)(Wl3 + q*4);
        floatx4 wr4 = *(const floatx4*)(Wr3 + q*4);
#pragma unroll
        for (int rep = 0; rep < 3; rep++) {
            int n = grp + rep*32;
            if (n < NN) {
                float hv[4];
                unpack_bf4(hxrS[n*32 + hswz(n, q)], hv);
                float al = hv[0]*wl4[0] + hv[1]*wl4[1] + hv[2]*wl4[2] + hv[3]*wl4[3];
                float ar = hv[0]*wr4[0] + hv[1]*wr4[1] + hv[2]*wr4[2] + hv[3]*wr4[3];
                al += __shfl_xor(al, 16); ar += __shfl_xor(ar, 16);
                al += __shfl_xor(al, 8);  ar += __shfl_xor(ar, 8);
                al += __shfl_xor(al, 4);  ar += __shfl_xor(ar, 4);
                al += __shfl_xor(al, 2);  ar += __shfl_xor(ar, 2);
                al += __shfl_xor(al, 1);  ar += __shfl_xor(ar, 1);
                if (q == 0) {
                    xl3S[n] = al + bl3[0];
                    xr3S[n] = ar + br3[0];
                }
            }
        }
    }
    __syncthreads();

    {
        float w0 = We3[0], w1 = We3[1], w2 = We3[2], w3 = We3[3], w4 = We3[4];
        float a0 = att3[0];
        for (int e = t; e < ED; e += TPB) {
            int src, dst;
            if (e < EKNN) { dst = e / KK; src = nbr[e]; }
            else { src = e - EKNN; dst = src + NAG; if (!gmask[src]) continue; }
            float s = xl3S[src] + xr3S[dst]
                    + eaS[e*5+0]*w0 + eaS[e*5+1]*w1 + eaS[e*5+2]*w2
                    + eaS[e*5+3]*w3 + eaS[e*5+4]*w4;
            s = fmaxf(s, 0.2f*s);
            logitS[e] = s * a0;
        }
    }
    __syncthreads();

    seg_softmax(logitS, gmask, alphaS, t);
    __syncthreads();

    // final: sum over agent nodes of (bias3 + sum_e alpha*xl3[src]); broadcast to 32 outputs
    float v = 0.f;
    if (t < NAG) {
        v = bias3[0];
#pragma unroll
        for (int k = 0; k < KK; k++) v += alphaS[t*KK + k] * xl3S[nbr[t*KK + k]];
    }
    if (t < 64) {
#pragma unroll
        for (int o = 32; o > 0; o >>= 1) v += __shfl_xor(v, o);
        if (t == 0) resS = v;
    }
    __syncthreads();
    if (t < NAG) out[g*NAG + t] = resS;
}

extern "C" void kernel_launch(void* const* d_in, const int* in_sizes, int n_in,
                              void* d_out, int out_size, void* d_ws, size_t ws_size,
                              hipStream_t stream)
{
    const float* obst = (const float*)d_in[0];
    const float* apos = (const float*)d_in[1];
    const float* gpos = (const float*)d_in[2];
    const float* avel = (const float*)d_in[3];
    const int B = in_sizes[1] / (NAG * 2);

    e3_kernel<<<B, TPB, 0, stream>>>(
        obst, apos, gpos, avel,
        (const float*)d_in[4],  (const float*)d_in[5],  (const float*)d_in[6],
        (const float*)d_in[7],  (const float*)d_in[8],  (const float*)d_in[9],
        (const float*)d_in[10],
        (const float*)d_in[11], (const float*)d_in[12], (const float*)d_in[13],
        (const float*)d_in[14], (const float*)d_in[15], (const float*)d_in[16],
        (const float*)d_in[17],
        (const float*)d_in[18], (const float*)d_in[19], (const float*)d_in[20],
        (const float*)d_in[21], (const float*)d_in[22], (const float*)d_in[23],
        (const float*)d_in[24],
        (float*)d_out);
}

// Round 11
// 225.933 us; speedup vs baseline: 1.3465x; 1.3465x over previous
//
#include <hip/hip_runtime.h>
#include <math.h>

typedef float floatx4 __attribute__((ext_vector_type(4)));

#define NAG   32
#define NOBS  16
#define NN    80
#define KK    5
#define EKNN  400   // NN*KK
#define ED    416   // EKNN + NOBS
#define HID   128
#define TPB   1024

// swizzle for bf16 rows (32 uint2-chunks of 4 bf16 per row)
__device__ __forceinline__ int hswz(int n, int p) { return p ^ ((n & 3) << 3); }

__device__ __forceinline__ float bfhi_f(unsigned u) {
    union { unsigned u; float f; } v; v.u = u & 0xffff0000u; return v.f;
}
__device__ __forceinline__ float bflo_f(unsigned u) {
    union { unsigned u; float f; } v; v.u = u << 16; return v.f;
}
__device__ __forceinline__ unsigned f_bf_rne(float f) {   // 16-bit bf16 in low bits
    union { float f; unsigned u; } v; v.f = f;
    return (v.u + 0x7fffu + ((v.u >> 16) & 1u)) >> 16;
}
__device__ __forceinline__ uint2 pack_bf4(float a, float b, float c, float d) {
    uint2 r;
    r.x = f_bf_rne(a) | (f_bf_rne(b) << 16);
    r.y = f_bf_rne(c) | (f_bf_rne(d) << 16);
    return r;
}
__device__ __forceinline__ void unpack_bf4(uint2 p, float* o) {
    o[0] = bflo_f(p.x); o[1] = bfhi_f(p.x);
    o[2] = bflo_f(p.y); o[3] = bfhi_f(p.y);
}

// ---- single node-linear pass: dst = h@W + b (bf16 -> dstB) ----
// Called twice per layer (Wl->xlB, then Wr->hxrS). Thread: q = t&31 (f4 col),
// ng = t>>5 (0..31) owns nodes {ng, ng+32, ng+64 if ng<16}. acc[3][4] = 12 regs;
// live set ~28 -> fits the 32-VGPR budget of launch_bounds(1024,8).
// Alias safety (dstB == hxr_in on the 2nd pass): h[n] is read ONLY by half-wave
// ng = n%32 (rows n0,n1,n2 are all == ng mod 32), and that same half-wave writes
// xr[n] after all its reads -> program order protects; no other thread touches it.
template<int F_IN>
__device__ __forceinline__ void nl_pass(const float* xf, const uint2* hxr_in,
    const float* __restrict__ W, const float* __restrict__ bv,
    uint2* dstB, int t)
{
    const int q  = t & 31;
    const int ng = t >> 5;                 // 0..31
    const int n0 = ng, n1 = ng + 32, n2 = 64 + (ng & 15);
    const bool v2 = (ng < 16);

    float acc[3][4];
#pragma unroll
    for (int a = 0; a < 3; a++)
#pragma unroll
        for (int c = 0; c < 4; c++) acc[a][c] = 0.f;

    if constexpr (F_IN == 5) {
#pragma unroll
        for (int fi = 0; fi < 5; ++fi) {
            floatx4 wv = *(const floatx4*)(W + fi*HID + q*4);
            float h0 = xf[n0*5 + fi], h1 = xf[n1*5 + fi], h2 = xf[n2*5 + fi];
#pragma unroll
            for (int c = 0; c < 4; c++) {
                acc[0][c] += h0*wv[c];
                acc[1][c] += h1*wv[c];
                acc[2][c] += h2*wv[c];
            }
        }
    } else {
        const int ro0 = n0*32, rs0 = (n0 & 3) << 3;
        const int ro1 = n1*32, rs1 = (n1 & 3) << 3;
        const int ro2 = n2*32, rs2 = (n2 & 3) << 3;
#pragma unroll 1
        for (int f4 = 0; f4 < F_IN/4; ++f4) {
            uint2 p0 = hxr_in[ro0 + (f4 ^ rs0)];   // half-wave broadcast reads
            uint2 p1 = hxr_in[ro1 + (f4 ^ rs1)];
            uint2 p2 = hxr_in[ro2 + (f4 ^ rs2)];
#pragma unroll
            for (int u = 0; u < 4; u++) {
                floatx4 wv = *(const floatx4*)(W + (f4*4 + u)*HID + q*4);
                unsigned w0 = (u < 2) ? p0.x : p0.y;
                unsigned w1 = (u < 2) ? p1.x : p1.y;
                unsigned w2 = (u < 2) ? p2.x : p2.y;
                float h0 = (u & 1) ? bfhi_f(w0) : bflo_f(w0);
                float h1 = (u & 1) ? bfhi_f(w1) : bflo_f(w1);
                float h2 = (u & 1) ? bfhi_f(w2) : bflo_f(w2);
#pragma unroll
                for (int c = 0; c < 4; c++) {
                    acc[0][c] += h0*wv[c];
                    acc[1][c] += h1*wv[c];
                    acc[2][c] += h2*wv[c];
                }
            }
        }
    }

    floatx4 b4 = *(const floatx4*)(bv + q*4);
    dstB[n0*32 + hswz(n0, q)] =
        pack_bf4(acc[0][0]+b4[0], acc[0][1]+b4[1], acc[0][2]+b4[2], acc[0][3]+b4[3]);
    dstB[n1*32 + hswz(n1, q)] =
        pack_bf4(acc[1][0]+b4[0], acc[1][1]+b4[1], acc[1][2]+b4[2], acc[1][3]+b4[3]);
    if (v2)
        dstB[n2*32 + hswz(n2, q)] =
            pack_bf4(acc[2][0]+b4[0], acc[2][1]+b4[1], acc[2][2]+b4[2], acc[2][3]+b4[3]);
}

// ---- edge logits: lane owns f4 col q = t&31, group t>>5 owns 13 edges ----
// We/att read from LDS per edge (keeps VGPR live-set ~22; conflict-free: q varies)
__device__ __forceinline__ void edge_logits(const uint2* xlB, const uint2* xrB,
    const float* eaS, const int* nbr, const int* gmask,
    const float* weS, const float* attS, float* logitS, int t)
{
    const int q   = t & 31;
    const int grp = t >> 5;      // 0..31, edges grp*13 .. grp*13+12

#pragma unroll 1
    for (int i = 0; i < 13; i++) {
        int e = grp*13 + i;
        int src, dst; bool act = true;
        if (e < EKNN) { dst = e / KK; src = nbr[e]; }
        else { int j = e - EKNN; src = j; dst = j + NAG; act = (gmask[j] != 0); }
        float vl[4], vr[4];
        unpack_bf4(xlB[src*32 + hswz(src, q)], vl);
        unpack_bf4(xrB[dst*32 + hswz(dst, q)], vr);
        floatx4 sv;
#pragma unroll
        for (int c = 0; c < 4; c++) sv[c] = vl[c] + vr[c];
#pragma unroll
        for (int j = 0; j < 5; j++) {
            float ej = eaS[e*5 + j];
            floatx4 wj = ((const floatx4*)weS)[j*32 + q];
#pragma unroll
            for (int c = 0; c < 4; c++) sv[c] += ej * wj[c];
        }
        floatx4 at = ((const floatx4*)attS)[q];
        float part = 0.f;
#pragma unroll
        for (int c = 0; c < 4; c++) {
            float s = fmaxf(sv[c], 0.2f*sv[c]);   // leaky_relu(s, 0.2)
            part += s * at[c];
        }
        part += __shfl_xor(part, 16);
        part += __shfl_xor(part, 8);
        part += __shfl_xor(part, 4);
        part += __shfl_xor(part, 2);
        part += __shfl_xor(part, 1);
        if (q == 0 && act) logitS[e] = part;
    }
}

// ---- per-dst softmax over incoming edges (5 knn + optional goal edge) ----
__device__ __forceinline__ void seg_softmax(const float* logitS, const int* gmask,
                                            float* alphaS, int t)
{
    if (t < NN) {
        const int n = t;
        float l[KK];
#pragma unroll
        for (int k = 0; k < KK; k++) l[k] = logitS[n*KK + k];
        float m = l[0];
#pragma unroll
        for (int k = 1; k < KK; k++) m = fmaxf(m, l[k]);
        int ge = -1; float lg = 0.f;
        if (n >= NAG && n < NAG + NOBS && gmask[n - NAG]) {
            ge = EKNN + (n - NAG);
            lg = logitS[ge];
            m = fmaxf(m, lg);
        }
        float s = 0.f, av[KK];
#pragma unroll
        for (int k = 0; k < KK; k++) { av[k] = expf(l[k] - m); s += av[k]; }
        float ag = 0.f;
        if (ge >= 0) { ag = expf(lg - m); s += ag; }
        float inv = 1.f / s;
#pragma unroll
        for (int k = 0; k < KK; k++) alphaS[n*KK + k] = av[k]*inv;
        if (ge >= 0) alphaS[ge] = ag*inv;
    }
}

// ---- h[n][f] = relu(bias[f] + sum_e alpha_e * xl[src_e][f]) -> bf16 hxrS ----
__device__ __forceinline__ void aggregate(const uint2* xlB, const float* alphaS,
                                          const int* nbr, const int* gmask,
                                          const float* __restrict__ bias,
                                          uint2* hxr, int t)
{
    for (int idx = t; idx < NN*32; idx += TPB) {
        int n = idx >> 5;
        int c = idx & 31;
        floatx4 acc = *(const floatx4*)(bias + 4*c);
#pragma unroll
        for (int k = 0; k < KK; k++) {
            float a = alphaS[n*KK + k];
            int s = nbr[n*KK + k];
            float v[4];
            unpack_bf4(xlB[s*32 + hswz(s, c)], v);
#pragma unroll
            for (int q = 0; q < 4; q++) acc[q] += a * v[q];
        }
        if (n >= NAG && n < NAG + NOBS && gmask[n - NAG]) {
            float a = alphaS[EKNN + (n - NAG)];
            int s = n - NAG;
            float v[4];
            unpack_bf4(xlB[s*32 + hswz(s, c)], v);
#pragma unroll
            for (int q = 0; q < 4; q++) acc[q] += a * v[q];
        }
#pragma unroll
        for (int q = 0; q < 4; q++) acc[q] = fmaxf(acc[q], 0.f);
        hxr[n*32 + hswz(n, c)] = pack_bf4(acc[0], acc[1], acc[2], acc[3]);
    }
}

// launch_bounds(1024, 8) == r7's attribute (the ONLY config that co-scheduled
// 2 blocks/CU: vgpr=32 -> 89% occupancy; 48/56/64 all -> 47%). This build's
// hot-loop live set is dieted to ~28 regs so the 32-budget holds WITHOUT r7's
// 270MB spill. LDS ~61.5KB, 2x <= 160KB.
__global__ __launch_bounds__(TPB, 8) void e3_kernel(
    const float* __restrict__ obst, const float* __restrict__ apos,
    const float* __restrict__ gpos, const float* __restrict__ avel,
    const float* __restrict__ Wl1, const float* __restrict__ bl1,
    const float* __restrict__ Wr1, const float* __restrict__ br1,
    const float* __restrict__ We1, const float* __restrict__ att1, const float* __restrict__ bias1,
    const float* __restrict__ Wl2, const float* __restrict__ bl2,
    const float* __restrict__ Wr2, const float* __restrict__ br2,
    const float* __restrict__ We2, const float* __restrict__ att2, const float* __restrict__ bias2,
    const float* __restrict__ Wl3, const float* __restrict__ bl3,
    const float* __restrict__ Wr3, const float* __restrict__ br3,
    const float* __restrict__ We3, const float* __restrict__ att3, const float* __restrict__ bias3,
    float* __restrict__ out)
{
    __shared__ float pos0[NN], pos1[NN], vel0[NN], vel1[NN], rad[NN];
    __shared__ float xfeat[NN*5];
    __shared__ int   nbr[NN*KK];
    __shared__ int   gmask[NOBS];
    __shared__ float eaS[ED*5];
    __shared__ float logitS[ED];
    __shared__ float alphaS[ED];
    __shared__ uint2 hxrS[NN*32];            // bf16 h AND bf16 xr (time-shared)
    __shared__ uint2 xlB[NN*32];             // bf16 xl
    __shared__ float weS[5*HID];
    __shared__ float attS[HID];
    __shared__ float xl3S[NN], xr3S[NN];
    __shared__ float resS;

    const int g = blockIdx.x;
    const int t = threadIdx.x;

    // ---------- phase A: load graph ----------
    if (t < NN) {
        int n = t;
        float px, py, vx = 0.f, vy = 0.f, r;
        if (n < NAG) {
            px = apos[(g*NAG + n)*2 + 0]; py = apos[(g*NAG + n)*2 + 1];
            vx = avel[(g*NAG + n)*2 + 0]; vy = avel[(g*NAG + n)*2 + 1];
            r = 0.05f;
        } else if (n < 2*NAG) {
            int m = n - NAG;
            px = gpos[(g*NAG + m)*2 + 0]; py = gpos[(g*NAG + m)*2 + 1];
            r = 0.f;
        } else {
            int m = n - 2*NAG;
            px = obst[(g*NOBS + m)*2 + 0]; py = obst[(g*NOBS + m)*2 + 1];
            r = 0.1f;
        }
        pos0[n] = px; pos1[n] = py; vel0[n] = vx; vel1[n] = vy; rad[n] = r;
        xfeat[n*5 + 0] = (n < NAG) ? 1.f : 0.f;
        xfeat[n*5 + 1] = (n >= NAG && n < 2*NAG) ? 1.f : 0.f;
        xfeat[n*5 + 2] = (n >= 2*NAG) ? 1.f : 0.f;
        xfeat[n*5 + 3] = (n < NAG) ? sqrtf(__fadd_rn(__fmul_rn(vx,vx), __fmul_rn(vy,vy))) : 0.f;
        xfeat[n*5 + 4] = r;
    }
    __syncthreads();

    // ---------- phase B: kNN top-5 (ascending d2, stable on ties == top_k) ----------
    if (t < NN) {
        const int i = t;
        float bd[KK]; int bi[KK];
#pragma unroll
        for (int k = 0; k < KK; k++) { bd[k] = 3.4e38f; bi[k] = -1; }
        const float pix = pos0[i], piy = pos1[i];
        for (int j = 0; j < NN; j++) {
            float dx = __fsub_rn(pix, pos0[j]);
            float dy = __fsub_rn(piy, pos1[j]);
            float d2 = __fadd_rn(__fmul_rn(dx,dx), __fmul_rn(dy,dy));
            if (d2 < bd[KK-1]) {
                int p = KK - 1;
                while (p > 0 && d2 < bd[p-1]) { bd[p] = bd[p-1]; bi[p] = bi[p-1]; p--; }
                bd[p] = d2; bi[p] = j;
            }
        }
#pragma unroll
        for (int k = 0; k < KK; k++) nbr[i*KK + k] = bi[k];
    }
    __syncthreads();

    // goal-edge dedup mask
    if (t < NOBS) {
        int j = t, dup = 0;
#pragma unroll
        for (int k = 0; k < KK; k++) dup |= (nbr[(NAG + j)*KK + k] == j);
        gmask[j] = !dup;
    }
    __syncthreads();

    // ---------- phase C: edge attributes ----------
    for (int e = t; e < ED; e += TPB) {
        int src, dst;
        if (e < EKNN) { dst = e / KK; src = nbr[e]; }
        else          { src = e - EKNN; dst = src + NAG; }
        float pdx = pos0[src] - pos0[dst];
        float pdy = pos1[src] - pos1[dst];
        float dist = sqrtf(pdx*pdx + pdy*pdy);
        float inv = 1.f / fmaxf(dist, 1e-6f);
        float pnx = pdx * inv, pny = pdy * inv;
        float rvx = vel0[src] - vel0[dst];
        float rvy = vel1[src] - vel1[dst];
        eaS[e*5 + 0] = (src < NAG && dst == src + NAG) ? 1.f : 0.f;
        eaS[e*5 + 1] = dist;
        eaS[e*5 + 2] = dist - (rad[src] + rad[dst]);
        eaS[e*5 + 3] = rvx*pnx + rvy*pny;
        eaS[e*5 + 4] = rvx*pny - rvy*pnx;
    }
    __syncthreads();

    // ================= layers 1 & 2 (F_out = 128) =================
    const float* WlA[2]   = { Wl1, Wl2 };
    const float* blA[2]   = { bl1, bl2 };
    const float* WrA[2]   = { Wr1, Wr2 };
    const float* brA[2]   = { br1, br2 };
    const float* WeA[2]   = { We1, We2 };
    const float* attA[2]  = { att1, att2 };
    const float* biasA[2] = { bias1, bias2 };

    for (int L = 0; L < 2; L++) {
        // stage We/att into LDS (visibility guaranteed by the post-GEMM barrier)
        for (int i = t; i < 5*HID; i += TPB) weS[i] = WeA[L][i];
        for (int i = t; i < HID;  i += TPB) attS[i] = attA[L][i];

        if (L == 0) {
            nl_pass<5>(xfeat, hxrS, WlA[0], blA[0], xlB,  t);
            nl_pass<5>(xfeat, hxrS, WrA[0], brA[0], hxrS, t);
        } else {
            nl_pass<HID>(xfeat, hxrS, WlA[1], blA[1], xlB,  t);
            nl_pass<HID>(xfeat, hxrS, WrA[1], brA[1], hxrS, t);   // h->xr alias, safe
        }
        __syncthreads();

        edge_logits(xlB, hxrS, eaS, nbr, gmask, weS, attS, logitS, t);
        __syncthreads();

        seg_softmax(logitS, gmask, alphaS, t);
        __syncthreads();

        aggregate(xlB, alphaS, nbr, gmask, biasA[L], hxrS, t);
        __syncthreads();
    }

    // ================= layer 3 (F_out = 1) =================
    // node transform: lane owns col q, group grp handles nodes grp, grp+32, grp+64
    {
        const int q   = t & 31;
        const int grp = t >> 5;
        floatx4 wl4 = *(const floatx4*)(Wl3 + q*4);
        floatx4 wr4 = *(const floatx4*)(Wr3 + q*4);
#pragma unroll
        for (int rep = 0; rep < 3; rep++) {
            int n = grp + rep*32;
            if (n < NN) {
                float hv[4];
                unpack_bf4(hxrS[n*32 + hswz(n, q)], hv);
                float al = hv[0]*wl4[0] + hv[1]*wl4[1] + hv[2]*wl4[2] + hv[3]*wl4[3];
                float ar = hv[0]*wr4[0] + hv[1]*wr4[1] + hv[2]*wr4[2] + hv[3]*wr4[3];
                al += __shfl_xor(al, 16); ar += __shfl_xor(ar, 16);
                al += __shfl_xor(al, 8);  ar += __shfl_xor(ar, 8);
                al += __shfl_xor(al, 4);  ar += __shfl_xor(ar, 4);
                al += __shfl_xor(al, 2);  ar += __shfl_xor(ar, 2);
                al += __shfl_xor(al, 1);  ar += __shfl_xor(ar, 1);
                if (q == 0) {
                    xl3S[n] = al + bl3[0];
                    xr3S[n] = ar + br3[0];
                }
            }
        }
    }
    __syncthreads();

    {
        float w0 = We3[0], w1 = We3[1], w2 = We3[2], w3 = We3[3], w4 = We3[4];
        float a0 = att3[0];
        for (int e = t; e < ED; e += TPB) {
            int src, dst;
            if (e < EKNN) { dst = e / KK; src = nbr[e]; }
            else { src = e - EKNN; dst = src + NAG; if (!gmask[src]) continue; }
            float s = xl3S[src] + xr3S[dst]
                    + eaS[e*5+0]*w0 + eaS[e*5+1]*w1 + eaS[e*5+2]*w2
                    + eaS[e*5+3]*w3 + eaS[e*5+4]*w4;
            s = fmaxf(s, 0.2f*s);
            logitS[e] = s * a0;
        }
    }
    __syncthreads();

    seg_softmax(logitS, gmask, alphaS, t);
    __syncthreads();

    // final: sum over agent nodes of (bias3 + sum_e alpha*xl3[src]); broadcast to 32 outputs
    float v = 0.f;
    if (t < NAG) {
        v = bias3[0];
#pragma unroll
        for (int k = 0; k < KK; k++) v += alphaS[t*KK + k] * xl3S[nbr[t*KK + k]];
    }
    if (t < 64) {
#pragma unroll
        for (int o = 32; o > 0; o >>= 1) v += __shfl_xor(v, o);
        if (t == 0) resS = v;
    }
    __syncthreads();
    if (t < NAG) out[g*NAG + t] = resS;
}

extern "C" void kernel_launch(void* const* d_in, const int* in_sizes, int n_in,
                              void* d_out, int out_size, void* d_ws, size_t ws_size,
                              hipStream_t stream)
{
    const float* obst = (const float*)d_in[0];
    const float* apos = (const float*)d_in[1];
    const float* gpos = (const float*)d_in[2];
    const float* avel = (const float*)d_in[3];
    const int B = in_sizes[1] / (NAG * 2);

    e3_kernel<<<B, TPB, 0, stream>>>(
        obst, apos, gpos, avel,
        (const float*)d_in[4],  (const float*)d_in[5],  (const float*)d_in[6],
        (const float*)d_in[7],  (const float*)d_in[8],  (const float*)d_in[9],
        (const float*)d_in[10],
        (const float*)d_in[11], (const float*)d_in[12], (const float*)d_in[13],
        (const float*)d_in[14], (const float*)d_in[15], (const float*)d_in[16],
        (const float*)d_in[17],
        (const float*)d_in[18], (const float*)d_in[19], (const float*)d_in[20],
        (const float*)d_in[21], (const float*)d_in[22], (const float*)d_in[23],
        (const float*)d_in[24],
        (float*)d_out);
}